// Round 5
// baseline (1184.370 us; speedup 1.0000x reference)
//
#include <hip/hip_runtime.h>
#include <stdint.h>

// ---------------- Threefry-2x32 (exact JAX implementation) ----------------
__host__ __device__ inline uint32_t rotl32(uint32_t x, int r) {
    return (x << r) | (x >> (32 - r));
}

__host__ __device__ inline void tf2x32(uint32_t k0, uint32_t k1,
                                       uint32_t x0, uint32_t x1,
                                       uint32_t& o0, uint32_t& o1) {
    const uint32_t ks0 = k0, ks1 = k1, ks2 = k0 ^ k1 ^ 0x1BD11BDAu;
    x0 += ks0; x1 += ks1;
    // round group 0 (13,15,26,6)
    x0 += x1; x1 = rotl32(x1, 13); x1 ^= x0;
    x0 += x1; x1 = rotl32(x1, 15); x1 ^= x0;
    x0 += x1; x1 = rotl32(x1, 26); x1 ^= x0;
    x0 += x1; x1 = rotl32(x1, 6);  x1 ^= x0;
    x0 += ks1; x1 += ks2 + 1u;
    // group 1 (17,29,16,24)
    x0 += x1; x1 = rotl32(x1, 17); x1 ^= x0;
    x0 += x1; x1 = rotl32(x1, 29); x1 ^= x0;
    x0 += x1; x1 = rotl32(x1, 16); x1 ^= x0;
    x0 += x1; x1 = rotl32(x1, 24); x1 ^= x0;
    x0 += ks2; x1 += ks0 + 2u;
    // group 2 (13,15,26,6)
    x0 += x1; x1 = rotl32(x1, 13); x1 ^= x0;
    x0 += x1; x1 = rotl32(x1, 15); x1 ^= x0;
    x0 += x1; x1 = rotl32(x1, 26); x1 ^= x0;
    x0 += x1; x1 = rotl32(x1, 6);  x1 ^= x0;
    x0 += ks0; x1 += ks1 + 3u;
    // group 3 (17,29,16,24)
    x0 += x1; x1 = rotl32(x1, 17); x1 ^= x0;
    x0 += x1; x1 = rotl32(x1, 29); x1 ^= x0;
    x0 += x1; x1 = rotl32(x1, 16); x1 ^= x0;
    x0 += x1; x1 = rotl32(x1, 24); x1 ^= x0;
    x0 += ks1; x1 += ks2 + 4u;
    // group 4 (13,15,26,6)
    x0 += x1; x1 = rotl32(x1, 13); x1 ^= x0;
    x0 += x1; x1 = rotl32(x1, 15); x1 ^= x0;
    x0 += x1; x1 = rotl32(x1, 26); x1 ^= x0;
    x0 += x1; x1 = rotl32(x1, 6);  x1 ^= x0;
    x0 += ks2; x1 += ks0 + 5u;
    o0 = x0; o1 = x1;
}

// PARTITIONABLE threefry dropout keep decision for flat element idx.
// Modern JAX (jax_threefry_partitionable=True, the default):
//   counts = iota(uint64); (b1,b2) = threefry2x32(key, (hi=counts>>32, lo=counts));
//   bits32 = b1 ^ b2;  keep = uniform < 0.5  <=>  bits32 < 2^31.
__device__ inline bool tf_keep(uint32_t idx, uint32_t k0, uint32_t k1) {
    uint32_t o0, o1;
    tf2x32(k0, k1, 0u, idx, o0, o1);
    return ((o0 ^ o1) >> 31) == 0u;
}

// ---------------- edge_index dtype detection ----------------
// flag64 = 1 if the edge buffer is int64 (odd words all zero), 0 if int32.
__global__ void detect_kernel(const int* __restrict__ w, int* __restrict__ flag64) {
    __shared__ int s[256];
    int t = threadIdx.x;
    int acc = 0;
    for (int i = t; i < 2048; i += 256) acc |= w[2 * i + 1];
    s[t] = acc;
    __syncthreads();
    for (int off = 128; off > 0; off >>= 1) {
        if (t < off) s[t] |= s[t + off];
        __syncthreads();
    }
    if (t == 0) *flag64 = (s[0] == 0) ? 1 : 0;
}

__device__ inline int edge_src(const int* w, int e, int f64) {
    return f64 ? w[2 * e] : w[e];
}
__device__ inline int edge_dst(const int* w, int e, int E, int f64) {
    return f64 ? w[2 * E + 2 * e] : w[E + e];
}

// ---------------- CSR construction ----------------
__global__ void hist_kernel(const int* __restrict__ w, const int* __restrict__ flag64,
                            int* __restrict__ deg, int E) {
    int f64 = *flag64;
    for (int e = blockIdx.x * blockDim.x + threadIdx.x; e < E; e += gridDim.x * blockDim.x)
        atomicAdd(&deg[edge_dst(w, e, E, f64)], 1);
}

__global__ void scan1_kernel(const int* __restrict__ deg, int* __restrict__ rowptr,
                             int* __restrict__ bsum, int n) {
    __shared__ int s[512];
    int t = threadIdx.x;
    int i = blockIdx.x * 512 + t;
    int v = (i < n) ? deg[i] : 0;
    s[t] = v;
    __syncthreads();
    for (int off = 1; off < 512; off <<= 1) {
        int x = (t >= off) ? s[t - off] : 0;
        __syncthreads();
        s[t] += x;
        __syncthreads();
    }
    if (i < n) rowptr[i + 1] = s[t];
    if (t == 511) bsum[blockIdx.x] = s[511];
}

__global__ void scan2_kernel(int* __restrict__ bsum, int nb) {
    if (threadIdx.x == 0 && blockIdx.x == 0) {
        int run = 0;
        for (int b = 0; b < nb; ++b) { int tmp = bsum[b]; bsum[b] = run; run += tmp; }
    }
}

__global__ void scan3_kernel(int* __restrict__ rowptr, const int* __restrict__ bsum, int n) {
    int i = blockIdx.x * 512 + threadIdx.x;
    if (i < n) rowptr[i + 1] += bsum[blockIdx.x];
    if (i == 0) rowptr[0] = 0;
}

__global__ void copycur_kernel(const int* __restrict__ rowptr, int* __restrict__ cursor, int n) {
    int i = blockIdx.x * blockDim.x + threadIdx.x;
    if (i < n) cursor[i] = rowptr[i];
}

__global__ void scatter_kernel(const int* __restrict__ w, const int* __restrict__ flag64,
                               int* __restrict__ cursor, int* __restrict__ col, int E) {
    int f64 = *flag64;
    for (int e = blockIdx.x * blockDim.x + threadIdx.x; e < E; e += gridDim.x * blockDim.x) {
        int d = edge_dst(w, e, E, f64);
        int p = atomicAdd(&cursor[d], 1);
        col[p] = edge_src(w, e, f64);
    }
}

// ---------------- GEMM: Y[M,N] = X[M,128] @ W[128,N] (+bias) ----------------
__global__ __launch_bounds__(256) void gemm128_kernel(
        const float* __restrict__ X, const float* __restrict__ W,
        const float* __restrict__ bias, float* __restrict__ Y, int M, int N) {
    __shared__ float Xs[64][128];  // 32 KB
    __shared__ float Ws[128][64];  // 32 KB

    const int row0 = blockIdx.x * 64;
    const int col0 = blockIdx.y * 64;
    const int t = threadIdx.x;

    {
        int r = t >> 5;
        int c = (t & 31) * 4;
#pragma unroll
        for (int it = 0; it < 8; ++it) {
            int rr = it * 8 + r;
            int gr = row0 + rr;
            float4 v = make_float4(0.f, 0.f, 0.f, 0.f);
            if (gr < M) v = *(const float4*)(X + (size_t)gr * 128 + c);
            *(float4*)(&Xs[rr][c]) = v;
        }
    }
    {
        int k = t >> 4;
        int c = (t & 15) * 4;
#pragma unroll
        for (int it = 0; it < 8; ++it) {
            int kk = it * 16 + k;
            *(float4*)(&Ws[kk][c]) = *(const float4*)(W + (size_t)kk * N + col0 + c);
        }
    }
    __syncthreads();

    const int tx = t & 15, ty = t >> 4;
    const int r0 = ty * 4, c0 = tx * 4;
    float acc[4][4] = {{0.f}};

#pragma unroll 8
    for (int k = 0; k < 128; k += 4) {
        float4 xv[4], wv[4];
#pragma unroll
        for (int i = 0; i < 4; ++i) xv[i] = *(const float4*)(&Xs[r0 + i][k]);
#pragma unroll
        for (int kk = 0; kk < 4; ++kk) wv[kk] = *(const float4*)(&Ws[k + kk][c0]);
#pragma unroll
        for (int i = 0; i < 4; ++i) {
            const float* xp = (const float*)&xv[i];
#pragma unroll
            for (int kk = 0; kk < 4; ++kk) {
                float xs = xp[kk];
                acc[i][0] += xs * wv[kk].x;
                acc[i][1] += xs * wv[kk].y;
                acc[i][2] += xs * wv[kk].z;
                acc[i][3] += xs * wv[kk].w;
            }
        }
    }

    float4 bv = make_float4(0.f, 0.f, 0.f, 0.f);
    if (bias) bv = *(const float4*)(bias + col0 + c0);
#pragma unroll
    for (int i = 0; i < 4; ++i) {
        int gr = row0 + r0 + i;
        if (gr >= M) continue;
        float4 o = make_float4(acc[i][0] + bv.x, acc[i][1] + bv.y,
                               acc[i][2] + bv.z, acc[i][3] + bv.w);
        *(float4*)(Y + (size_t)gr * N + col0 + c0) = o;
    }
}

// ---------------- aggregation epilogues ----------------
// one wave per node; 128 channels -> 2 per lane. mean + Z + relu + dropout.
__global__ __launch_bounds__(256) void agg128_kernel(
        const float* __restrict__ Yl, const float* __restrict__ Z,
        const int* __restrict__ rowptr, const int* __restrict__ col,
        float* __restrict__ H, int n, uint32_t k0, uint32_t k1) {
    int node = blockIdx.x * 4 + (threadIdx.x >> 6);
    if (node >= n) return;
    int lane = threadIdx.x & 63;
    int c0 = lane * 2;
    int beg = rowptr[node], end = rowptr[node + 1];
    float ax = 0.f, ay = 0.f;
    for (int e = beg; e < end; ++e) {
        int j = col[e];
        float2 v = *(const float2*)(Yl + (size_t)j * 128 + c0);
        ax += v.x; ay += v.y;
    }
    int cnt = end - beg;
    float inv = 1.0f / (float)(cnt > 1 ? cnt : 1);
    float2 z = *(const float2*)(Z + (size_t)node * 128 + c0);
    float hx = fmaxf(ax * inv + z.x, 0.0f);
    float hy = fmaxf(ay * inv + z.y, 0.0f);
    uint32_t idx = (uint32_t)node * 128u + (uint32_t)c0;
    hx = tf_keep(idx, k0, k1)      ? hx * 2.0f : 0.0f;
    hy = tf_keep(idx + 1u, k0, k1) ? hy * 2.0f : 0.0f;
    float2 o; o.x = hx; o.y = hy;
    *(float2*)(H + (size_t)node * 128 + c0) = o;
}

// one wave per node; 64 channels -> 1 per lane. mean + Z, no activation. (final layer)
__global__ __launch_bounds__(256) void agg64_kernel(
        const float* __restrict__ Yl, const float* __restrict__ Z,
        const int* __restrict__ rowptr, const int* __restrict__ col,
        float* __restrict__ out, int n) {
    int node = blockIdx.x * 4 + (threadIdx.x >> 6);
    if (node >= n) return;
    int lane = threadIdx.x & 63;
    int beg = rowptr[node], end = rowptr[node + 1];
    float a = 0.f;
    for (int e = beg; e < end; ++e) {
        int j = col[e];
        a += Yl[(size_t)j * 64 + lane];
    }
    int cnt = end - beg;
    float inv = 1.0f / (float)(cnt > 1 ? cnt : 1);
    out[(size_t)node * 64 + lane] = a * inv + Z[(size_t)node * 64 + lane];
}

// ---------------- host ----------------
extern "C" void kernel_launch(void* const* d_in, const int* in_sizes, int n_in,
                              void* d_out, int out_size, void* d_ws, size_t ws_size,
                              hipStream_t stream) {
    const float* x   = (const float*)d_in[0];
    const int*   ei  = (const int*)d_in[1];   // int32 view; width detected on device
    const float* Wl0 = (const float*)d_in[2];
    const float* Wr0 = (const float*)d_in[3];
    const float* b0  = (const float*)d_in[4];
    const float* Wl1 = (const float*)d_in[5];
    const float* Wr1 = (const float*)d_in[6];
    const float* b1  = (const float*)d_in[7];
    const float* Wl2 = (const float*)d_in[8];
    const float* Wr2 = (const float*)d_in[9];
    const float* b2  = (const float*)d_in[10];

    const int N = in_sizes[0] / 128;     // 100000
    const int E = in_sizes[1] / 2;       // 1600000
    const int* srcp = ei;

    // workspace layout
    char* ws = (char*)d_ws;
    size_t off = 0;
    auto alloc = [&](size_t bytes) {
        size_t o = off;
        off = (off + bytes + 255) & ~(size_t)255;
        return o;
    };
    int*   rowptr = (int*)(ws + alloc((size_t)(N + 1) * 4));
    int*   deg    = (int*)(ws + alloc((size_t)N * 4));
    int*   cursor = (int*)(ws + alloc((size_t)N * 4));
    int*   bsum   = (int*)(ws + alloc(1024 * 4));
    int*   flag64 = (int*)(ws + alloc(256));
    int*   col    = (int*)(ws + alloc((size_t)E * 4));
    float* A      = (float*)(ws + alloc((size_t)N * 128 * 4));
    float* B      = (float*)(ws + alloc((size_t)N * 128 * 4));
    float* C      = (float*)(ws + alloc((size_t)N * 128 * 4));

    // dropout keys: jax.random.split(jax.random.key(42), 2) under the
    // PARTITIONABLE scheme (default in modern JAX): new key i = full
    // (o0,o1) output of threefry(key, hi=0, lo=i).
    uint32_t k00, k01, k10, k11;
    tf2x32(0u, 42u, 0u, 0u, k00, k01);   // dk[0] = (k00, k01)
    tf2x32(0u, 42u, 0u, 1u, k10, k11);   // dk[1] = (k10, k11)

    // ---- CSR build ----
    detect_kernel<<<1, 256, 0, stream>>>(srcp, flag64);
    hipMemsetAsync(deg, 0, (size_t)N * 4, stream);
    hist_kernel<<<2048, 256, 0, stream>>>(srcp, flag64, deg, E);
    int NB = (N + 511) / 512;
    scan1_kernel<<<NB, 512, 0, stream>>>(deg, rowptr, bsum, N);
    scan2_kernel<<<1, 64, 0, stream>>>(bsum, NB);
    scan3_kernel<<<NB, 512, 0, stream>>>(rowptr, bsum, N);
    copycur_kernel<<<(N + 255) / 256, 256, 0, stream>>>(rowptr, cursor, N);
    scatter_kernel<<<2048, 256, 0, stream>>>(srcp, flag64, cursor, col, E);

    dim3 blk(256);
    dim3 g128((N + 63) / 64, 2);
    dim3 g64((N + 63) / 64, 1);
    dim3 gagg((N + 3) / 4);

    // ---- layer 0 ----
    gemm128_kernel<<<g128, blk, 0, stream>>>(x, Wl0, nullptr, B, N, 128);
    gemm128_kernel<<<g128, blk, 0, stream>>>(x, Wr0, b0, C, N, 128);
    agg128_kernel<<<gagg, blk, 0, stream>>>(B, C, rowptr, col, A, N, k00, k01);
    // ---- layer 1 ----
    gemm128_kernel<<<g128, blk, 0, stream>>>(A, Wl1, nullptr, B, N, 128);
    gemm128_kernel<<<g128, blk, 0, stream>>>(A, Wr1, b1, C, N, 128);
    agg128_kernel<<<gagg, blk, 0, stream>>>(B, C, rowptr, col, C, N, k10, k11);
    // ---- layer 2 (project to 64 first, then aggregate) ----
    gemm128_kernel<<<g64, blk, 0, stream>>>(C, Wl2, nullptr, B, N, 64);
    gemm128_kernel<<<g64, blk, 0, stream>>>(C, Wr2, b2, A, N, 64);
    agg64_kernel<<<gagg, blk, 0, stream>>>(B, A, rowptr, col, (float*)d_out, N);
}

// Round 6
// 726.456 us; speedup vs baseline: 1.6303x; 1.6303x over previous
//
#include <hip/hip_runtime.h>
#include <stdint.h>

typedef __attribute__((ext_vector_type(8))) short s8v;   // 8 bf16 = 4 VGPRs (MFMA A/B frag)
typedef __attribute__((ext_vector_type(4))) float f4v;   // MFMA C/D frag

// ---------------- Threefry-2x32 (exact JAX implementation) ----------------
__host__ __device__ inline uint32_t rotl32(uint32_t x, int r) {
    return (x << r) | (x >> (32 - r));
}

__host__ __device__ inline void tf2x32(uint32_t k0, uint32_t k1,
                                       uint32_t x0, uint32_t x1,
                                       uint32_t& o0, uint32_t& o1) {
    const uint32_t ks0 = k0, ks1 = k1, ks2 = k0 ^ k1 ^ 0x1BD11BDAu;
    x0 += ks0; x1 += ks1;
    x0 += x1; x1 = rotl32(x1, 13); x1 ^= x0;
    x0 += x1; x1 = rotl32(x1, 15); x1 ^= x0;
    x0 += x1; x1 = rotl32(x1, 26); x1 ^= x0;
    x0 += x1; x1 = rotl32(x1, 6);  x1 ^= x0;
    x0 += ks1; x1 += ks2 + 1u;
    x0 += x1; x1 = rotl32(x1, 17); x1 ^= x0;
    x0 += x1; x1 = rotl32(x1, 29); x1 ^= x0;
    x0 += x1; x1 = rotl32(x1, 16); x1 ^= x0;
    x0 += x1; x1 = rotl32(x1, 24); x1 ^= x0;
    x0 += ks2; x1 += ks0 + 2u;
    x0 += x1; x1 = rotl32(x1, 13); x1 ^= x0;
    x0 += x1; x1 = rotl32(x1, 15); x1 ^= x0;
    x0 += x1; x1 = rotl32(x1, 26); x1 ^= x0;
    x0 += x1; x1 = rotl32(x1, 6);  x1 ^= x0;
    x0 += ks0; x1 += ks1 + 3u;
    x0 += x1; x1 = rotl32(x1, 17); x1 ^= x0;
    x0 += x1; x1 = rotl32(x1, 29); x1 ^= x0;
    x0 += x1; x1 = rotl32(x1, 16); x1 ^= x0;
    x0 += x1; x1 = rotl32(x1, 24); x1 ^= x0;
    x0 += ks1; x1 += ks2 + 4u;
    x0 += x1; x1 = rotl32(x1, 13); x1 ^= x0;
    x0 += x1; x1 = rotl32(x1, 15); x1 ^= x0;
    x0 += x1; x1 = rotl32(x1, 26); x1 ^= x0;
    x0 += x1; x1 = rotl32(x1, 6);  x1 ^= x0;
    x0 += ks2; x1 += ks0 + 5u;
    o0 = x0; o1 = x1;
}

// PARTITIONABLE threefry dropout: bits = o0^o1 of tf(key, hi=0, lo=idx); keep <=> bits < 2^31.
__device__ inline bool tf_keep(uint32_t idx, uint32_t k0, uint32_t k1) {
    uint32_t o0, o1;
    tf2x32(k0, k1, 0u, idx, o0, o1);
    return ((o0 ^ o1) >> 31) == 0u;
}

// ---------------- bf16 helpers ----------------
__device__ inline uint16_t f2bf(float f) {
    uint32_t u = __float_as_uint(f);
    return (uint16_t)((u + 0x7fffu + ((u >> 16) & 1u)) >> 16);   // RNE
}
__device__ inline float bflo(uint32_t v) { return __uint_as_float(v << 16); }
__device__ inline float bfhi(uint32_t v) { return __uint_as_float(v & 0xffff0000u); }

// ---------------- edge_index dtype detection ----------------
__global__ void detect_kernel(const int* __restrict__ w, int* __restrict__ flag64) {
    __shared__ int s[256];
    int t = threadIdx.x;
    int acc = 0;
    for (int i = t; i < 2048; i += 256) acc |= w[2 * i + 1];
    s[t] = acc;
    __syncthreads();
    for (int off = 128; off > 0; off >>= 1) {
        if (t < off) s[t] |= s[t + off];
        __syncthreads();
    }
    if (t == 0) *flag64 = (s[0] == 0) ? 1 : 0;
}

__device__ inline int edge_src(const int* w, int e, int f64) {
    return f64 ? w[2 * e] : w[e];
}
__device__ inline int edge_dst(const int* w, int e, int E, int f64) {
    return f64 ? w[2 * E + 2 * e] : w[E + e];
}

// ---------------- CSR construction ----------------
__global__ void hist_kernel(const int* __restrict__ w, const int* __restrict__ flag64,
                            int* __restrict__ deg, int E) {
    int f64 = *flag64;
    for (int e = blockIdx.x * blockDim.x + threadIdx.x; e < E; e += gridDim.x * blockDim.x)
        atomicAdd(&deg[edge_dst(w, e, E, f64)], 1);
}

__global__ void scan1_kernel(const int* __restrict__ deg, int* __restrict__ rowptr,
                             int* __restrict__ bsum, int n) {
    __shared__ int s[512];
    int t = threadIdx.x;
    int i = blockIdx.x * 512 + t;
    int v = (i < n) ? deg[i] : 0;
    s[t] = v;
    __syncthreads();
    for (int off = 1; off < 512; off <<= 1) {
        int x = (t >= off) ? s[t - off] : 0;
        __syncthreads();
        s[t] += x;
        __syncthreads();
    }
    if (i < n) rowptr[i + 1] = s[t];
    if (t == 511) bsum[blockIdx.x] = s[511];
}

__global__ void scan2_kernel(int* __restrict__ bsum, int nb) {
    if (threadIdx.x == 0 && blockIdx.x == 0) {
        int run = 0;
        for (int b = 0; b < nb; ++b) { int tmp = bsum[b]; bsum[b] = run; run += tmp; }
    }
}

__global__ void scan3_kernel(int* __restrict__ rowptr, const int* __restrict__ bsum, int n) {
    int i = blockIdx.x * 512 + threadIdx.x;
    if (i < n) rowptr[i + 1] += bsum[blockIdx.x];
    if (i == 0) rowptr[0] = 0;
}

__global__ void copycur_kernel(const int* __restrict__ rowptr, int* __restrict__ cursor, int n) {
    int i = blockIdx.x * blockDim.x + threadIdx.x;
    if (i < n) cursor[i] = rowptr[i];
}

__global__ void scatter_kernel(const int* __restrict__ w, const int* __restrict__ flag64,
                               int* __restrict__ cursor, int* __restrict__ col, int E) {
    int f64 = *flag64;
    for (int e = blockIdx.x * blockDim.x + threadIdx.x; e < E; e += gridDim.x * blockDim.x) {
        int d = edge_dst(w, e, E, f64);
        int p = atomicAdd(&cursor[d], 1);
        col[p] = edge_src(w, e, f64);
    }
}

// ---------------- fp32 -> bf16 converts ----------------
__global__ void convx_kernel(const float* __restrict__ in, uint16_t* __restrict__ out, int n4) {
    int i = blockIdx.x * blockDim.x + threadIdx.x;
    if (i >= n4) return;
    float4 v = *(const float4*)(in + (size_t)i * 4);
    uint16_t o[4] = { f2bf(v.x), f2bf(v.y), f2bf(v.z), f2bf(v.w) };
    *(uint2*)(out + (size_t)i * 4) = *(uint2*)o;
}

// transpose + convert: W [K=128][N] fp32 -> Wt [N][128] bf16
__global__ void convw_kernel(const float* __restrict__ W, uint16_t* __restrict__ Wt, int N) {
    int i = blockIdx.x * blockDim.x + threadIdx.x;  // i = n*128 + k
    if (i >= N * 128) return;
    int n = i >> 7, k = i & 127;
    Wt[i] = f2bf(W[(size_t)k * N + n]);
}

// ---------------- paired MFMA GEMM ----------------
// YL[M][N](bf16) = X@Wl ; Z[M][N](f32) = X@Wr + b.  X bf16 [M][128], Wt* bf16 [N][128] (B^T form).
// Block 256 = 4 waves; wave owns 16 rows x all N cols. LDS-free (A rows unique; W is L2-hot).
// Fragment mapping (m97/m89-verified): A: lane l holds X[row0+(l&15)][kg*8..+7], kg=l>>4;
// B: lane l holds Wt[n0+(l&15)][kg*8..+7]; D: row=(l>>4)*4+reg, col=l&15.
__global__ __launch_bounds__(256) void pair_gemm_kernel(
        const uint16_t* __restrict__ Xb, const uint16_t* __restrict__ WtL,
        const uint16_t* __restrict__ WtR, const float* __restrict__ bias,
        uint16_t* __restrict__ YL, float* __restrict__ Z, int M, int N) {
    const int l   = threadIdx.x & 63;
    const int wv  = threadIdx.x >> 6;
    const int row0 = blockIdx.x * 64 + wv * 16;
    const int ml  = l & 15;
    const int kg  = l >> 4;

    int arow = row0 + ml; if (arow >= M) arow = M - 1;
    const uint16_t* xr = Xb + (size_t)arow * 128 + kg * 8;
    s8v a0 = *(const s8v*)(xr);
    s8v a1 = *(const s8v*)(xr + 32);
    s8v a2 = *(const s8v*)(xr + 64);
    s8v a3 = *(const s8v*)(xr + 96);

    const int drow = row0 + kg * 4;   // D rows drow..drow+3, D col = n0+ml

    for (int n0 = 0; n0 < N; n0 += 16) {
        const uint16_t* wl = WtL + (size_t)(n0 + ml) * 128 + kg * 8;
        const uint16_t* wr = WtR + (size_t)(n0 + ml) * 128 + kg * 8;
        f4v accL = {0.f, 0.f, 0.f, 0.f};
        f4v accR = {0.f, 0.f, 0.f, 0.f};
        accL = __builtin_amdgcn_mfma_f32_16x16x32_bf16(a0, *(const s8v*)(wl), accL, 0, 0, 0);
        accR = __builtin_amdgcn_mfma_f32_16x16x32_bf16(a0, *(const s8v*)(wr), accR, 0, 0, 0);
        accL = __builtin_amdgcn_mfma_f32_16x16x32_bf16(a1, *(const s8v*)(wl + 32), accL, 0, 0, 0);
        accR = __builtin_amdgcn_mfma_f32_16x16x32_bf16(a1, *(const s8v*)(wr + 32), accR, 0, 0, 0);
        accL = __builtin_amdgcn_mfma_f32_16x16x32_bf16(a2, *(const s8v*)(wl + 64), accL, 0, 0, 0);
        accR = __builtin_amdgcn_mfma_f32_16x16x32_bf16(a2, *(const s8v*)(wr + 64), accR, 0, 0, 0);
        accL = __builtin_amdgcn_mfma_f32_16x16x32_bf16(a3, *(const s8v*)(wl + 96), accL, 0, 0, 0);
        accR = __builtin_amdgcn_mfma_f32_16x16x32_bf16(a3, *(const s8v*)(wr + 96), accR, 0, 0, 0);

        float bv = bias[n0 + ml];
#pragma unroll
        for (int r = 0; r < 4; ++r) {
            int g = drow + r;
            if (g < M) {
                YL[(size_t)g * N + n0 + ml] = f2bf(accL[r]);
                Z [(size_t)g * N + n0 + ml] = accR[r] + bv;
            }
        }
    }
}

// ---------------- aggregation epilogues ----------------
// wave per node, 128 ch -> lane owns 2 (one packed uint). mean + Z + relu + dropout -> H bf16.
__global__ __launch_bounds__(256) void agg128_kernel(
        const uint16_t* __restrict__ Yl, const float* __restrict__ Z,
        const int* __restrict__ rowptr, const int* __restrict__ col,
        uint16_t* __restrict__ H, int n, uint32_t k0, uint32_t k1) {
    int node = blockIdx.x * 4 + (threadIdx.x >> 6);
    if (node >= n) return;
    int lane = threadIdx.x & 63;
    const uint32_t* ylp = (const uint32_t*)Yl;
    int beg = rowptr[node], end = rowptr[node + 1];
    float ax = 0.f, ay = 0.f;
    int e = beg;
    for (; e + 3 < end; e += 4) {
        int j0 = col[e], j1 = col[e + 1], j2 = col[e + 2], j3 = col[e + 3];
        uint32_t v0 = ylp[(size_t)j0 * 64 + lane];
        uint32_t v1 = ylp[(size_t)j1 * 64 + lane];
        uint32_t v2 = ylp[(size_t)j2 * 64 + lane];
        uint32_t v3 = ylp[(size_t)j3 * 64 + lane];
        ax += bflo(v0) + bflo(v1) + bflo(v2) + bflo(v3);
        ay += bfhi(v0) + bfhi(v1) + bfhi(v2) + bfhi(v3);
    }
    for (; e < end; ++e) {
        uint32_t v = ylp[(size_t)col[e] * 64 + lane];
        ax += bflo(v); ay += bfhi(v);
    }
    int cnt = end - beg;
    float inv = 1.0f / (float)(cnt > 1 ? cnt : 1);
    float2 z = *(const float2*)(Z + (size_t)node * 128 + lane * 2);
    float hx = fmaxf(ax * inv + z.x, 0.0f);
    float hy = fmaxf(ay * inv + z.y, 0.0f);
    uint32_t idx = (uint32_t)node * 128u + (uint32_t)lane * 2u;
    hx = tf_keep(idx, k0, k1)      ? hx * 2.0f : 0.0f;
    hy = tf_keep(idx + 1u, k0, k1) ? hy * 2.0f : 0.0f;
    uint32_t packed = (uint32_t)f2bf(hx) | ((uint32_t)f2bf(hy) << 16);
    ((uint32_t*)H)[(size_t)node * 64 + lane] = packed;
}

// final layer: 64 ch, lane owns 1. mean + Z -> fp32 out. Yl bf16 [N][64].
__global__ __launch_bounds__(256) void agg64_kernel(
        const uint16_t* __restrict__ Yl, const float* __restrict__ Z,
        const int* __restrict__ rowptr, const int* __restrict__ col,
        float* __restrict__ out, int n) {
    int node = blockIdx.x * 4 + (threadIdx.x >> 6);
    if (node >= n) return;
    int lane = threadIdx.x & 63;
    int beg = rowptr[node], end = rowptr[node + 1];
    float a = 0.f;
    int e = beg;
    for (; e + 3 < end; e += 4) {
        int j0 = col[e], j1 = col[e + 1], j2 = col[e + 2], j3 = col[e + 3];
        float v0 = bflo((uint32_t)Yl[(size_t)j0 * 64 + lane] << 0) ; // bf16 -> f32 via shift below
        // (load as ushort, widen)
        v0 = __uint_as_float(((uint32_t)Yl[(size_t)j0 * 64 + lane]) << 16);
        float v1 = __uint_as_float(((uint32_t)Yl[(size_t)j1 * 64 + lane]) << 16);
        float v2 = __uint_as_float(((uint32_t)Yl[(size_t)j2 * 64 + lane]) << 16);
        float v3 = __uint_as_float(((uint32_t)Yl[(size_t)j3 * 64 + lane]) << 16);
        a += v0 + v1 + v2 + v3;
    }
    for (; e < end; ++e)
        a += __uint_as_float(((uint32_t)Yl[(size_t)col[e] * 64 + lane]) << 16);
    int cnt = end - beg;
    float inv = 1.0f / (float)(cnt > 1 ? cnt : 1);
    out[(size_t)node * 64 + lane] = a * inv + Z[(size_t)node * 64 + lane];
}

// ---------------- host ----------------
extern "C" void kernel_launch(void* const* d_in, const int* in_sizes, int n_in,
                              void* d_out, int out_size, void* d_ws, size_t ws_size,
                              hipStream_t stream) {
    const float* x   = (const float*)d_in[0];
    const int*   ei  = (const int*)d_in[1];
    const float* Wl0 = (const float*)d_in[2];
    const float* Wr0 = (const float*)d_in[3];
    const float* b0  = (const float*)d_in[4];
    const float* Wl1 = (const float*)d_in[5];
    const float* Wr1 = (const float*)d_in[6];
    const float* b1  = (const float*)d_in[7];
    const float* Wl2 = (const float*)d_in[8];
    const float* Wr2 = (const float*)d_in[9];
    const float* b2  = (const float*)d_in[10];

    const int N = in_sizes[0] / 128;     // 100000
    const int E = in_sizes[1] / 2;       // 1600000
    const int* srcp = ei;

    char* ws = (char*)d_ws;
    size_t off = 0;
    auto alloc = [&](size_t bytes) {
        size_t o = off;
        off = (off + bytes + 255) & ~(size_t)255;
        return o;
    };
    int*      rowptr = (int*)(ws + alloc((size_t)(N + 1) * 4));
    int*      deg    = (int*)(ws + alloc((size_t)N * 4));
    int*      cursor = (int*)(ws + alloc((size_t)N * 4));
    int*      bsum   = (int*)(ws + alloc(1024 * 4));
    int*      flag64 = (int*)(ws + alloc(256));
    int*      col    = (int*)(ws + alloc((size_t)E * 4));
    uint16_t* Xb     = (uint16_t*)(ws + alloc((size_t)N * 128 * 2));
    uint16_t* Hb     = (uint16_t*)(ws + alloc((size_t)N * 128 * 2));
    uint16_t* Byl    = (uint16_t*)(ws + alloc((size_t)N * 128 * 2));
    float*    Cz     = (float*)(ws + alloc((size_t)N * 128 * 4));
    uint16_t* Wt0l   = (uint16_t*)(ws + alloc(128 * 128 * 2));
    uint16_t* Wt0r   = (uint16_t*)(ws + alloc(128 * 128 * 2));
    uint16_t* Wt1l   = (uint16_t*)(ws + alloc(128 * 128 * 2));
    uint16_t* Wt1r   = (uint16_t*)(ws + alloc(128 * 128 * 2));
    uint16_t* Wt2l   = (uint16_t*)(ws + alloc(128 * 128 * 2));
    uint16_t* Wt2r   = (uint16_t*)(ws + alloc(128 * 128 * 2));

    // dropout keys: jax.random.split(jax.random.key(42), 2), partitionable scheme.
    uint32_t k00, k01, k10, k11;
    tf2x32(0u, 42u, 0u, 0u, k00, k01);   // dk[0]
    tf2x32(0u, 42u, 0u, 1u, k10, k11);   // dk[1]

    // ---- CSR build ----
    detect_kernel<<<1, 256, 0, stream>>>(srcp, flag64);
    hipMemsetAsync(deg, 0, (size_t)N * 4, stream);
    hist_kernel<<<2048, 256, 0, stream>>>(srcp, flag64, deg, E);
    int NB = (N + 511) / 512;
    scan1_kernel<<<NB, 512, 0, stream>>>(deg, rowptr, bsum, N);
    scan2_kernel<<<1, 64, 0, stream>>>(bsum, NB);
    scan3_kernel<<<NB, 512, 0, stream>>>(rowptr, bsum, N);
    copycur_kernel<<<(N + 255) / 256, 256, 0, stream>>>(rowptr, cursor, N);
    scatter_kernel<<<2048, 256, 0, stream>>>(srcp, flag64, cursor, col, E);

    // ---- converts ----
    convx_kernel<<<(N * 128 / 4 + 255) / 256, 256, 0, stream>>>(x, Xb, N * 128 / 4);
    convw_kernel<<<64, 256, 0, stream>>>(Wl0, Wt0l, 128);
    convw_kernel<<<64, 256, 0, stream>>>(Wr0, Wt0r, 128);
    convw_kernel<<<64, 256, 0, stream>>>(Wl1, Wt1l, 128);
    convw_kernel<<<64, 256, 0, stream>>>(Wr1, Wt1r, 128);
    convw_kernel<<<32, 256, 0, stream>>>(Wl2, Wt2l, 64);
    convw_kernel<<<32, 256, 0, stream>>>(Wr2, Wt2r, 64);

    dim3 blk(256);
    dim3 gg((N + 63) / 64);
    dim3 gagg((N + 3) / 4);

    // ---- layer 0 ----
    pair_gemm_kernel<<<gg, blk, 0, stream>>>(Xb, Wt0l, Wt0r, b0, Byl, Cz, N, 128);
    agg128_kernel<<<gagg, blk, 0, stream>>>(Byl, Cz, rowptr, col, Hb, N, k00, k01);
    // ---- layer 1 ----
    pair_gemm_kernel<<<gg, blk, 0, stream>>>(Hb, Wt1l, Wt1r, b1, Byl, Cz, N, 128);
    agg128_kernel<<<gagg, blk, 0, stream>>>(Byl, Cz, rowptr, col, Hb, N, k10, k11);
    // ---- layer 2: project (128->64) then aggregate ----
    pair_gemm_kernel<<<gg, blk, 0, stream>>>(Hb, Wt2l, Wt2r, b2, Byl, Cz, N, 64);
    agg64_kernel<<<gagg, blk, 0, stream>>>(Byl, Cz, rowptr, col, (float*)d_out, N);
}

// Round 9
// 625.968 us; speedup vs baseline: 1.8921x; 1.1605x over previous
//
#include <hip/hip_runtime.h>
#include <stdint.h>

typedef __attribute__((ext_vector_type(8))) short s8v;   // 8 bf16 = 4 VGPRs (MFMA A/B frag)
typedef __attribute__((ext_vector_type(4))) float f4v;   // MFMA C/D frag

constexpr int ECHUNK = 4096;   // edges per bucket-count/scatter block

// ---------------- Threefry-2x32 (exact JAX implementation) ----------------
__host__ __device__ inline uint32_t rotl32(uint32_t x, int r) {
    return (x << r) | (x >> (32 - r));
}

__host__ __device__ inline void tf2x32(uint32_t k0, uint32_t k1,
                                       uint32_t x0, uint32_t x1,
                                       uint32_t& o0, uint32_t& o1) {
    const uint32_t ks0 = k0, ks1 = k1, ks2 = k0 ^ k1 ^ 0x1BD11BDAu;
    x0 += ks0; x1 += ks1;
    x0 += x1; x1 = rotl32(x1, 13); x1 ^= x0;
    x0 += x1; x1 = rotl32(x1, 15); x1 ^= x0;
    x0 += x1; x1 = rotl32(x1, 26); x1 ^= x0;
    x0 += x1; x1 = rotl32(x1, 6);  x1 ^= x0;
    x0 += ks1; x1 += ks2 + 1u;
    x0 += x1; x1 = rotl32(x1, 17); x1 ^= x0;
    x0 += x1; x1 = rotl32(x1, 29); x1 ^= x0;
    x0 += x1; x1 = rotl32(x1, 16); x1 ^= x0;
    x0 += x1; x1 = rotl32(x1, 24); x1 ^= x0;
    x0 += ks2; x1 += ks0 + 2u;
    x0 += x1; x1 = rotl32(x1, 13); x1 ^= x0;
    x0 += x1; x1 = rotl32(x1, 15); x1 ^= x0;
    x0 += x1; x1 = rotl32(x1, 26); x1 ^= x0;
    x0 += x1; x1 = rotl32(x1, 6);  x1 ^= x0;
    x0 += ks0; x1 += ks1 + 3u;
    x0 += x1; x1 = rotl32(x1, 17); x1 ^= x0;
    x0 += x1; x1 = rotl32(x1, 29); x1 ^= x0;
    x0 += x1; x1 = rotl32(x1, 16); x1 ^= x0;
    x0 += x1; x1 = rotl32(x1, 24); x1 ^= x0;
    x0 += ks1; x1 += ks2 + 4u;
    x0 += x1; x1 = rotl32(x1, 13); x1 ^= x0;
    x0 += x1; x1 = rotl32(x1, 15); x1 ^= x0;
    x0 += x1; x1 = rotl32(x1, 26); x1 ^= x0;
    x0 += x1; x1 = rotl32(x1, 6);  x1 ^= x0;
    x0 += ks2; x1 += ks0 + 5u;
    o0 = x0; o1 = x1;
}

// PARTITIONABLE threefry dropout: bits = o0^o1 of tf(key, hi=0, lo=idx); keep <=> bits < 2^31.
__device__ inline bool tf_keep(uint32_t idx, uint32_t k0, uint32_t k1) {
    uint32_t o0, o1;
    tf2x32(k0, k1, 0u, idx, o0, o1);
    return ((o0 ^ o1) >> 31) == 0u;
}

// ---------------- bf16 helpers ----------------
__device__ inline uint16_t f2bf(float f) {
    uint32_t u = __float_as_uint(f);
    return (uint16_t)((u + 0x7fffu + ((u >> 16) & 1u)) >> 16);   // RNE
}
__device__ inline float bflo(uint32_t v) { return __uint_as_float(v << 16); }
__device__ inline float bfhi(uint32_t v) { return __uint_as_float(v & 0xffff0000u); }

// ---------------- edge_index dtype detection ----------------
__global__ void detect_kernel(const int* __restrict__ w, int* __restrict__ flag64) {
    __shared__ int s[256];
    int t = threadIdx.x;
    int acc = 0;
    for (int i = t; i < 2048; i += 256) acc |= w[2 * i + 1];
    s[t] = acc;
    __syncthreads();
    for (int off = 128; off > 0; off >>= 1) {
        if (t < off) s[t] |= s[t + off];
        __syncthreads();
    }
    if (t == 0) *flag64 = (s[0] == 0) ? 1 : 0;
}

__device__ inline int edge_src(const int* w, int e, int f64) {
    return f64 ? w[2 * e] : w[e];
}
__device__ inline int edge_dst(const int* w, int e, int E, int f64) {
    return f64 ? w[2 * E + 2 * e] : w[E + e];
}

// ---------------- bucketed CSR construction ----------------
// Buckets of 512 node ids (bucket = dst >> 9). Bucket-major segmented layout:
// bucket b, count-block blk owns segment hist[b*nA + blk]; after exclusive scan
// (bofs), bucket b's edges are the contiguous range [bofs[b*nA], bofs[(b+1)*nA]).

// Phase A: per-block LDS bucket histogram.
__global__ __launch_bounds__(256) void bucketcount_kernel(
        const int* __restrict__ w, const int* __restrict__ flag64,
        int* __restrict__ hist, int E, int nA, int NBUK) {
    __shared__ int cnt[256];
    int t = threadIdx.x;
    if (t < NBUK) cnt[t] = 0;
    __syncthreads();
    int f64 = *flag64;
    int lo = blockIdx.x * ECHUNK, hi = min(E, lo + ECHUNK);
    for (int e = lo + t; e < hi; e += 256)
        atomicAdd(&cnt[edge_dst(w, e, E, f64) >> 9], 1);
    __syncthreads();
    if (t < NBUK) hist[t * nA + blockIdx.x] = cnt[t];
}

// generic scan (exclusive into out[0..n], out[0]=0, out[n]=total)
__global__ void scan1_kernel(const int* __restrict__ in, int* __restrict__ out,
                             int* __restrict__ bsum, int n) {
    __shared__ int s[512];
    int t = threadIdx.x;
    int i = blockIdx.x * 512 + t;
    int v = (i < n) ? in[i] : 0;
    s[t] = v;
    __syncthreads();
    for (int off = 1; off < 512; off <<= 1) {
        int x = (t >= off) ? s[t - off] : 0;
        __syncthreads();
        s[t] += x;
        __syncthreads();
    }
    if (i < n) out[i + 1] = s[t];
    if (t == 511) bsum[blockIdx.x] = s[511];
}

__global__ void scan2_kernel(int* __restrict__ bsum, int nb) {
    if (threadIdx.x == 0 && blockIdx.x == 0) {
        int run = 0;
        for (int b = 0; b < nb; ++b) { int tmp = bsum[b]; bsum[b] = run; run += tmp; }
    }
}

__global__ void scan3_kernel(int* __restrict__ out, const int* __restrict__ bsum, int n) {
    int i = blockIdx.x * 512 + threadIdx.x;
    if (i < n) out[i + 1] += bsum[blockIdx.x];
    if (i == 0) out[0] = 0;
}

// Phase C: scatter (src,dst) pairs into bucket-major segments (coalesced-ish runs).
__global__ __launch_bounds__(256) void bucketscatter_kernel(
        const int* __restrict__ w, const int* __restrict__ flag64,
        const int* __restrict__ bofs, uint2* __restrict__ tmp, int E, int nA, int NBUK) {
    __shared__ int sbase[256];
    int t = threadIdx.x;
    if (t < NBUK) sbase[t] = bofs[t * nA + blockIdx.x];
    __syncthreads();
    int f64 = *flag64;
    int lo = blockIdx.x * ECHUNK, hi = min(E, lo + ECHUNK);
    for (int e = lo + t; e < hi; e += 256) {
        int s = edge_src(w, e, f64);
        int d = edge_dst(w, e, E, f64);
        int p = atomicAdd(&sbase[d >> 9], 1);
        tmp[p] = make_uint2((unsigned)s, (unsigned)d);
    }
}

// Phase D0: per-bucket degree count (LDS counters; one block owns one bucket).
__global__ __launch_bounds__(256) void bucketdeg_kernel(
        const uint2* __restrict__ tmp, const int* __restrict__ bofs,
        int* __restrict__ deg, int nA, int N) {
    __shared__ int cnt[512];
    int b = blockIdx.x;
    int node0 = b << 9;
    int nn = min(512, N - node0);
    int t = threadIdx.x;
    for (int i = t; i < nn; i += 256) cnt[i] = 0;
    __syncthreads();
    int lo = bofs[b * nA], hi = bofs[(b + 1) * nA];
    for (int e = lo + t; e < hi; e += 256)
        atomicAdd(&cnt[(int)tmp[e].y - node0], 1);
    __syncthreads();
    for (int i = t; i < nn; i += 256) deg[node0 + i] = cnt[i];
}

// Phase D: fine scatter within bucket (LDS cursor; col window is L2-hot).
__global__ __launch_bounds__(256) void finescatter_kernel(
        const uint2* __restrict__ tmp, const int* __restrict__ bofs,
        const int* __restrict__ rowptr, int* __restrict__ col, int nA, int N) {
    __shared__ int cur[512];
    int b = blockIdx.x;
    int node0 = b << 9;
    int nn = min(512, N - node0);
    int t = threadIdx.x;
    for (int i = t; i < nn; i += 256) cur[i] = rowptr[node0 + i];
    __syncthreads();
    int lo = bofs[b * nA], hi = bofs[(b + 1) * nA];
    for (int e = lo + t; e < hi; e += 256) {
        uint2 p = tmp[e];
        int q = atomicAdd(&cur[(int)p.y - node0], 1);
        col[q] = (int)p.x;
    }
}

// ---------------- fp32 -> bf16 converts ----------------
__global__ void convx_kernel(const float* __restrict__ in, uint16_t* __restrict__ out, int n4) {
    int i = blockIdx.x * blockDim.x + threadIdx.x;
    if (i >= n4) return;
    float4 v = *(const float4*)(in + (size_t)i * 4);
    uint16_t o[4] = { f2bf(v.x), f2bf(v.y), f2bf(v.z), f2bf(v.w) };
    *(uint2*)(out + (size_t)i * 4) = *(uint2*)o;
}

// transpose + convert: W [K=128][N] fp32 -> Wt [N][128] bf16
__global__ void convw_kernel(const float* __restrict__ W, uint16_t* __restrict__ Wt, int N) {
    int i = blockIdx.x * blockDim.x + threadIdx.x;  // i = n*128 + k
    if (i >= N * 128) return;
    int n = i >> 7, k = i & 127;
    Wt[i] = f2bf(W[(size_t)k * N + n]);
}

// ---------------- paired MFMA GEMM ----------------
// YL[M][N](bf16) = X@Wl ; Z[M][N](f32) = X@Wr + b.  X bf16 [M][128], Wt* bf16 [N][128] (B^T).
__global__ __launch_bounds__(256) void pair_gemm_kernel(
        const uint16_t* __restrict__ Xb, const uint16_t* __restrict__ WtL,
        const uint16_t* __restrict__ WtR, const float* __restrict__ bias,
        uint16_t* __restrict__ YL, float* __restrict__ Z, int M, int N) {
    const int l   = threadIdx.x & 63;
    const int wv  = threadIdx.x >> 6;
    const int row0 = blockIdx.x * 64 + wv * 16;
    const int ml  = l & 15;
    const int kg  = l >> 4;

    int arow = row0 + ml; if (arow >= M) arow = M - 1;
    const uint16_t* xr = Xb + (size_t)arow * 128 + kg * 8;
    s8v a0 = *(const s8v*)(xr);
    s8v a1 = *(const s8v*)(xr + 32);
    s8v a2 = *(const s8v*)(xr + 64);
    s8v a3 = *(const s8v*)(xr + 96);

    const int drow = row0 + kg * 4;

    for (int n0 = 0; n0 < N; n0 += 16) {
        const uint16_t* wl = WtL + (size_t)(n0 + ml) * 128 + kg * 8;
        const uint16_t* wr = WtR + (size_t)(n0 + ml) * 128 + kg * 8;
        f4v accL = {0.f, 0.f, 0.f, 0.f};
        f4v accR = {0.f, 0.f, 0.f, 0.f};
        accL = __builtin_amdgcn_mfma_f32_16x16x32_bf16(a0, *(const s8v*)(wl), accL, 0, 0, 0);
        accR = __builtin_amdgcn_mfma_f32_16x16x32_bf16(a0, *(const s8v*)(wr), accR, 0, 0, 0);
        accL = __builtin_amdgcn_mfma_f32_16x16x32_bf16(a1, *(const s8v*)(wl + 32), accL, 0, 0, 0);
        accR = __builtin_amdgcn_mfma_f32_16x16x32_bf16(a1, *(const s8v*)(wr + 32), accR, 0, 0, 0);
        accL = __builtin_amdgcn_mfma_f32_16x16x32_bf16(a2, *(const s8v*)(wl + 64), accL, 0, 0, 0);
        accR = __builtin_amdgcn_mfma_f32_16x16x32_bf16(a2, *(const s8v*)(wr + 64), accR, 0, 0, 0);
        accL = __builtin_amdgcn_mfma_f32_16x16x32_bf16(a3, *(const s8v*)(wl + 96), accL, 0, 0, 0);
        accR = __builtin_amdgcn_mfma_f32_16x16x32_bf16(a3, *(const s8v*)(wr + 96), accR, 0, 0, 0);

        float bv = bias[n0 + ml];
#pragma unroll
        for (int r = 0; r < 4; ++r) {
            int g = drow + r;
            if (g < M) {
                YL[(size_t)g * N + n0 + ml] = f2bf(accL[r]);
                Z [(size_t)g * N + n0 + ml] = accR[r] + bv;
            }
        }
    }
}

// ---------------- aggregation epilogues ----------------
__global__ __launch_bounds__(256) void agg128_kernel(
        const uint16_t* __restrict__ Yl, const float* __restrict__ Z,
        const int* __restrict__ rowptr, const int* __restrict__ col,
        uint16_t* __restrict__ H, int n, uint32_t k0, uint32_t k1) {
    int node = blockIdx.x * 4 + (threadIdx.x >> 6);
    if (node >= n) return;
    int lane = threadIdx.x & 63;
    const uint32_t* ylp = (const uint32_t*)Yl;
    int beg = rowptr[node], end = rowptr[node + 1];
    float ax = 0.f, ay = 0.f;
    int e = beg;
    for (; e + 3 < end; e += 4) {
        int j0 = col[e], j1 = col[e + 1], j2 = col[e + 2], j3 = col[e + 3];
        uint32_t v0 = ylp[(size_t)j0 * 64 + lane];
        uint32_t v1 = ylp[(size_t)j1 * 64 + lane];
        uint32_t v2 = ylp[(size_t)j2 * 64 + lane];
        uint32_t v3 = ylp[(size_t)j3 * 64 + lane];
        ax += bflo(v0) + bflo(v1) + bflo(v2) + bflo(v3);
        ay += bfhi(v0) + bfhi(v1) + bfhi(v2) + bfhi(v3);
    }
    for (; e < end; ++e) {
        uint32_t v = ylp[(size_t)col[e] * 64 + lane];
        ax += bflo(v); ay += bfhi(v);
    }
    int cnt = end - beg;
    float inv = 1.0f / (float)(cnt > 1 ? cnt : 1);
    float2 z = *(const float2*)(Z + (size_t)node * 128 + lane * 2);
    float hx = fmaxf(ax * inv + z.x, 0.0f);
    float hy = fmaxf(ay * inv + z.y, 0.0f);
    uint32_t idx = (uint32_t)node * 128u + (uint32_t)lane * 2u;
    hx = tf_keep(idx, k0, k1)      ? hx * 2.0f : 0.0f;
    hy = tf_keep(idx + 1u, k0, k1) ? hy * 2.0f : 0.0f;
    uint32_t packed = (uint32_t)f2bf(hx) | ((uint32_t)f2bf(hy) << 16);
    ((uint32_t*)H)[(size_t)node * 64 + lane] = packed;
}

__global__ __launch_bounds__(256) void agg64_kernel(
        const uint16_t* __restrict__ Yl, const float* __restrict__ Z,
        const int* __restrict__ rowptr, const int* __restrict__ col,
        float* __restrict__ out, int n) {
    int node = blockIdx.x * 4 + (threadIdx.x >> 6);
    if (node >= n) return;
    int lane = threadIdx.x & 63;
    int beg = rowptr[node], end = rowptr[node + 1];
    float a = 0.f;
    int e = beg;
    for (; e + 3 < end; e += 4) {
        int j0 = col[e], j1 = col[e + 1], j2 = col[e + 2], j3 = col[e + 3];
        float v0 = __uint_as_float(((uint32_t)Yl[(size_t)j0 * 64 + lane]) << 16);
        float v1 = __uint_as_float(((uint32_t)Yl[(size_t)j1 * 64 + lane]) << 16);
        float v2 = __uint_as_float(((uint32_t)Yl[(size_t)j2 * 64 + lane]) << 16);
        float v3 = __uint_as_float(((uint32_t)Yl[(size_t)j3 * 64 + lane]) << 16);
        a += v0 + v1 + v2 + v3;
    }
    for (; e < end; ++e)
        a += __uint_as_float(((uint32_t)Yl[(size_t)col[e] * 64 + lane]) << 16);
    int cnt = end - beg;
    float inv = 1.0f / (float)(cnt > 1 ? cnt : 1);
    out[(size_t)node * 64 + lane] = a * inv + Z[(size_t)node * 64 + lane];
}

// ---------------- host ----------------
extern "C" void kernel_launch(void* const* d_in, const int* in_sizes, int n_in,
                              void* d_out, int out_size, void* d_ws, size_t ws_size,
                              hipStream_t stream) {
    const float* x   = (const float*)d_in[0];
    const int*   ei  = (const int*)d_in[1];
    const float* Wl0 = (const float*)d_in[2];
    const float* Wr0 = (const float*)d_in[3];
    const float* b0  = (const float*)d_in[4];
    const float* Wl1 = (const float*)d_in[5];
    const float* Wr1 = (const float*)d_in[6];
    const float* b1  = (const float*)d_in[7];
    const float* Wl2 = (const float*)d_in[8];
    const float* Wr2 = (const float*)d_in[9];
    const float* b2  = (const float*)d_in[10];

    const int N = in_sizes[0] / 128;     // 100000
    const int E = in_sizes[1] / 2;       // 1600000
    const int* srcp = ei;

    const int nA   = (E + ECHUNK - 1) / ECHUNK;      // bucket-count blocks
    const int NBUK = (N + 511) >> 9;                 // 512-node buckets (<=256)
    const int L    = NBUK * nA;                      // segmented hist length

    char* ws = (char*)d_ws;
    size_t off = 0;
    auto alloc = [&](size_t bytes) {
        size_t o = off;
        off = (off + bytes + 255) & ~(size_t)255;
        return o;
    };
    int*      rowptr = (int*)(ws + alloc((size_t)(N + 1) * 4));
    int*      deg    = (int*)(ws + alloc((size_t)N * 4));
    int*      bsum   = (int*)(ws + alloc(1024 * 4));
    int*      flag64 = (int*)(ws + alloc(256));
    int*      hist   = (int*)(ws + alloc((size_t)L * 4));
    int*      bofs   = (int*)(ws + alloc((size_t)(L + 1) * 4));
    uint2*    tmp    = (uint2*)(ws + alloc((size_t)E * 8));
    int*      col    = (int*)(ws + alloc((size_t)E * 4));
    uint16_t* Xb     = (uint16_t*)(ws + alloc((size_t)N * 128 * 2));
    uint16_t* Hb     = (uint16_t*)(ws + alloc((size_t)N * 128 * 2));
    uint16_t* Byl    = (uint16_t*)(ws + alloc((size_t)N * 128 * 2));
    float*    Cz     = (float*)(ws + alloc((size_t)N * 128 * 4));
    uint16_t* Wt0l   = (uint16_t*)(ws + alloc(128 * 128 * 2));
    uint16_t* Wt0r   = (uint16_t*)(ws + alloc(128 * 128 * 2));
    uint16_t* Wt1l   = (uint16_t*)(ws + alloc(128 * 128 * 2));
    uint16_t* Wt1r   = (uint16_t*)(ws + alloc(128 * 128 * 2));
    uint16_t* Wt2l   = (uint16_t*)(ws + alloc(128 * 128 * 2));
    uint16_t* Wt2r   = (uint16_t*)(ws + alloc(128 * 128 * 2));

    // dropout keys: jax.random.split(jax.random.key(42), 2), partitionable scheme.
    uint32_t k00, k01, k10, k11;
    tf2x32(0u, 42u, 0u, 0u, k00, k01);   // dk[0]
    tf2x32(0u, 42u, 0u, 1u, k10, k11);   // dk[1]

    // ---- bucketed CSR build ----
    detect_kernel<<<1, 256, 0, stream>>>(srcp, flag64);
    bucketcount_kernel<<<nA, 256, 0, stream>>>(srcp, flag64, hist, E, nA, NBUK);
    int NBL = (L + 511) / 512;
    scan1_kernel<<<NBL, 512, 0, stream>>>(hist, bofs, bsum, L);
    scan2_kernel<<<1, 64, 0, stream>>>(bsum, NBL);
    scan3_kernel<<<NBL, 512, 0, stream>>>(bofs, bsum, L);
    bucketscatter_kernel<<<nA, 256, 0, stream>>>(srcp, flag64, bofs, tmp, E, nA, NBUK);
    bucketdeg_kernel<<<NBUK, 256, 0, stream>>>(tmp, bofs, deg, nA, N);
    int NBN = (N + 511) / 512;
    scan1_kernel<<<NBN, 512, 0, stream>>>(deg, rowptr, bsum, N);
    scan2_kernel<<<1, 64, 0, stream>>>(bsum, NBN);
    scan3_kernel<<<NBN, 512, 0, stream>>>(rowptr, bsum, N);
    finescatter_kernel<<<NBUK, 256, 0, stream>>>(tmp, bofs, rowptr, col, nA, N);

    // ---- converts ----
    convx_kernel<<<(N * 128 / 4 + 255) / 256, 256, 0, stream>>>(x, Xb, N * 128 / 4);
    convw_kernel<<<64, 256, 0, stream>>>(Wl0, Wt0l, 128);
    convw_kernel<<<64, 256, 0, stream>>>(Wr0, Wt0r, 128);
    convw_kernel<<<64, 256, 0, stream>>>(Wl1, Wt1l, 128);
    convw_kernel<<<64, 256, 0, stream>>>(Wr1, Wt1r, 128);
    convw_kernel<<<32, 256, 0, stream>>>(Wl2, Wt2l, 64);
    convw_kernel<<<32, 256, 0, stream>>>(Wr2, Wt2r, 64);

    dim3 blk(256);
    dim3 gg((N + 63) / 64);
    dim3 gagg((N + 3) / 4);

    // ---- layer 0 ----
    pair_gemm_kernel<<<gg, blk, 0, stream>>>(Xb, Wt0l, Wt0r, b0, Byl, Cz, N, 128);
    agg128_kernel<<<gagg, blk, 0, stream>>>(Byl, Cz, rowptr, col, Hb, N, k00, k01);
    // ---- layer 1 ----
    pair_gemm_kernel<<<gg, blk, 0, stream>>>(Hb, Wt1l, Wt1r, b1, Byl, Cz, N, 128);
    agg128_kernel<<<gagg, blk, 0, stream>>>(Byl, Cz, rowptr, col, Hb, N, k10, k11);
    // ---- layer 2: project (128->64) then aggregate ----
    pair_gemm_kernel<<<gg, blk, 0, stream>>>(Hb, Wt2l, Wt2r, b2, Byl, Cz, N, 64);
    agg64_kernel<<<gagg, blk, 0, stream>>>(Byl, Cz, rowptr, col, (float*)d_out, N);
}

// Round 10
// 565.384 us; speedup vs baseline: 2.0948x; 1.1072x over previous
//
#include <hip/hip_runtime.h>
#include <stdint.h>

typedef __attribute__((ext_vector_type(8))) short s8v;   // 8 bf16 = 4 VGPRs (MFMA A/B frag)
typedef __attribute__((ext_vector_type(4))) float f4v;   // MFMA C/D frag

constexpr int ECHUNK = 4096;   // edges per bucket-count/scatter block

// ---------------- Threefry-2x32 (exact JAX implementation) ----------------
__host__ __device__ inline uint32_t rotl32(uint32_t x, int r) {
    return (x << r) | (x >> (32 - r));
}

__host__ __device__ inline void tf2x32(uint32_t k0, uint32_t k1,
                                       uint32_t x0, uint32_t x1,
                                       uint32_t& o0, uint32_t& o1) {
    const uint32_t ks0 = k0, ks1 = k1, ks2 = k0 ^ k1 ^ 0x1BD11BDAu;
    x0 += ks0; x1 += ks1;
    x0 += x1; x1 = rotl32(x1, 13); x1 ^= x0;
    x0 += x1; x1 = rotl32(x1, 15); x1 ^= x0;
    x0 += x1; x1 = rotl32(x1, 26); x1 ^= x0;
    x0 += x1; x1 = rotl32(x1, 6);  x1 ^= x0;
    x0 += ks1; x1 += ks2 + 1u;
    x0 += x1; x1 = rotl32(x1, 17); x1 ^= x0;
    x0 += x1; x1 = rotl32(x1, 29); x1 ^= x0;
    x0 += x1; x1 = rotl32(x1, 16); x1 ^= x0;
    x0 += x1; x1 = rotl32(x1, 24); x1 ^= x0;
    x0 += ks2; x1 += ks0 + 2u;
    x0 += x1; x1 = rotl32(x1, 13); x1 ^= x0;
    x0 += x1; x1 = rotl32(x1, 15); x1 ^= x0;
    x0 += x1; x1 = rotl32(x1, 26); x1 ^= x0;
    x0 += x1; x1 = rotl32(x1, 6);  x1 ^= x0;
    x0 += ks0; x1 += ks1 + 3u;
    x0 += x1; x1 = rotl32(x1, 17); x1 ^= x0;
    x0 += x1; x1 = rotl32(x1, 29); x1 ^= x0;
    x0 += x1; x1 = rotl32(x1, 16); x1 ^= x0;
    x0 += x1; x1 = rotl32(x1, 24); x1 ^= x0;
    x0 += ks1; x1 += ks2 + 4u;
    x0 += x1; x1 = rotl32(x1, 13); x1 ^= x0;
    x0 += x1; x1 = rotl32(x1, 15); x1 ^= x0;
    x0 += x1; x1 = rotl32(x1, 26); x1 ^= x0;
    x0 += x1; x1 = rotl32(x1, 6);  x1 ^= x0;
    x0 += ks2; x1 += ks0 + 5u;
    o0 = x0; o1 = x1;
}

// PARTITIONABLE threefry dropout: bits = o0^o1 of tf(key, hi=0, lo=idx); keep <=> bits < 2^31.
__device__ inline bool tf_keep(uint32_t idx, uint32_t k0, uint32_t k1) {
    uint32_t o0, o1;
    tf2x32(k0, k1, 0u, idx, o0, o1);
    return ((o0 ^ o1) >> 31) == 0u;
}

// ---------------- bf16 helpers ----------------
__device__ inline uint16_t f2bf(float f) {
    uint32_t u = __float_as_uint(f);
    return (uint16_t)((u + 0x7fffu + ((u >> 16) & 1u)) >> 16);   // RNE
}
__device__ inline float bflo(uint32_t v) { return __uint_as_float(v << 16); }
__device__ inline float bfhi(uint32_t v) { return __uint_as_float(v & 0xffff0000u); }

// ---------------- edge_index dtype detection ----------------
__global__ void detect_kernel(const int* __restrict__ w, int* __restrict__ flag64) {
    __shared__ int s[256];
    int t = threadIdx.x;
    int acc = 0;
    for (int i = t; i < 2048; i += 256) acc |= w[2 * i + 1];
    s[t] = acc;
    __syncthreads();
    for (int off = 128; off > 0; off >>= 1) {
        if (t < off) s[t] |= s[t + off];
        __syncthreads();
    }
    if (t == 0) *flag64 = (s[0] == 0) ? 1 : 0;
}

__device__ inline int edge_src(const int* w, int e, int f64) {
    return f64 ? w[2 * e] : w[e];
}
__device__ inline int edge_dst(const int* w, int e, int E, int f64) {
    return f64 ? w[2 * E + 2 * e] : w[E + e];
}

// ---------------- bucketed CSR construction ----------------
__global__ __launch_bounds__(256) void bucketcount_kernel(
        const int* __restrict__ w, const int* __restrict__ flag64,
        int* __restrict__ hist, int E, int nA, int NBUK) {
    __shared__ int cnt[256];
    int t = threadIdx.x;
    if (t < NBUK) cnt[t] = 0;
    __syncthreads();
    int f64 = *flag64;
    int lo = blockIdx.x * ECHUNK, hi = min(E, lo + ECHUNK);
    for (int e = lo + t; e < hi; e += 256)
        atomicAdd(&cnt[edge_dst(w, e, E, f64) >> 9], 1);
    __syncthreads();
    if (t < NBUK) hist[t * nA + blockIdx.x] = cnt[t];
}

__global__ void scan1_kernel(const int* __restrict__ in, int* __restrict__ out,
                             int* __restrict__ bsum, int n) {
    __shared__ int s[512];
    int t = threadIdx.x;
    int i = blockIdx.x * 512 + t;
    int v = (i < n) ? in[i] : 0;
    s[t] = v;
    __syncthreads();
    for (int off = 1; off < 512; off <<= 1) {
        int x = (t >= off) ? s[t - off] : 0;
        __syncthreads();
        s[t] += x;
        __syncthreads();
    }
    if (i < n) out[i + 1] = s[t];
    if (t == 511) bsum[blockIdx.x] = s[511];
}

__global__ void scan2_kernel(int* __restrict__ bsum, int nb) {
    if (threadIdx.x == 0 && blockIdx.x == 0) {
        int run = 0;
        for (int b = 0; b < nb; ++b) { int tmp = bsum[b]; bsum[b] = run; run += tmp; }
    }
}

__global__ void scan3_kernel(int* __restrict__ out, const int* __restrict__ bsum, int n) {
    int i = blockIdx.x * 512 + threadIdx.x;
    if (i < n) out[i + 1] += bsum[blockIdx.x];
    if (i == 0) out[0] = 0;
}

__global__ __launch_bounds__(256) void bucketscatter_kernel(
        const int* __restrict__ w, const int* __restrict__ flag64,
        const int* __restrict__ bofs, uint2* __restrict__ tmp, int E, int nA, int NBUK) {
    __shared__ int sbase[256];
    int t = threadIdx.x;
    if (t < NBUK) sbase[t] = bofs[t * nA + blockIdx.x];
    __syncthreads();
    int f64 = *flag64;
    int lo = blockIdx.x * ECHUNK, hi = min(E, lo + ECHUNK);
    for (int e = lo + t; e < hi; e += 256) {
        int s = edge_src(w, e, f64);
        int d = edge_dst(w, e, E, f64);
        int p = atomicAdd(&sbase[d >> 9], 1);
        tmp[p] = make_uint2((unsigned)s, (unsigned)d);
    }
}

__global__ __launch_bounds__(256) void bucketdeg_kernel(
        const uint2* __restrict__ tmp, const int* __restrict__ bofs,
        int* __restrict__ deg, int nA, int N) {
    __shared__ int cnt[512];
    int b = blockIdx.x;
    int node0 = b << 9;
    int nn = min(512, N - node0);
    int t = threadIdx.x;
    for (int i = t; i < nn; i += 256) cnt[i] = 0;
    __syncthreads();
    int lo = bofs[b * nA], hi = bofs[(b + 1) * nA];
    for (int e = lo + t; e < hi; e += 256)
        atomicAdd(&cnt[(int)tmp[e].y - node0], 1);
    __syncthreads();
    for (int i = t; i < nn; i += 256) deg[node0 + i] = cnt[i];
}

__global__ __launch_bounds__(256) void finescatter_kernel(
        const uint2* __restrict__ tmp, const int* __restrict__ bofs,
        const int* __restrict__ rowptr, int* __restrict__ col, int nA, int N) {
    __shared__ int cur[512];
    int b = blockIdx.x;
    int node0 = b << 9;
    int nn = min(512, N - node0);
    int t = threadIdx.x;
    for (int i = t; i < nn; i += 256) cur[i] = rowptr[node0 + i];
    __syncthreads();
    int lo = bofs[b * nA], hi = bofs[(b + 1) * nA];
    for (int e = lo + t; e < hi; e += 256) {
        uint2 p = tmp[e];
        int q = atomicAdd(&cur[(int)p.y - node0], 1);
        col[q] = (int)p.x;
    }
}

// ---------------- fp32 -> bf16 converts ----------------
__global__ void convx_kernel(const float* __restrict__ in, uint16_t* __restrict__ out, int n4) {
    int i = blockIdx.x * blockDim.x + threadIdx.x;
    if (i >= n4) return;
    float4 v = *(const float4*)(in + (size_t)i * 4);
    uint16_t o[4] = { f2bf(v.x), f2bf(v.y), f2bf(v.z), f2bf(v.w) };
    *(uint2*)(out + (size_t)i * 4) = *(uint2*)o;
}

// fused transpose+convert of all 6 weights: W [128][n] fp32 -> Wt [n][128] bf16
struct WPack {
    const float* src[6];
    uint16_t*    dst[6];
    int          n[6];
};
__global__ void convw_all_kernel(WPack p) {
    int s = blockIdx.y;
    int i = blockIdx.x * blockDim.x + threadIdx.x;   // i = n*128 + k
    int total = p.n[s] * 128;
    if (i >= total) return;
    int nn = i >> 7, k = i & 127;
    p.dst[s][i] = f2bf(p.src[s][(size_t)k * p.n[s] + nn]);
}

// ---------------- paired MFMA GEMM ----------------
// YL[M][N](bf16) = X@Wl ; ZB[M][N](bf16) = X@Wr + b.  X bf16 [M][128], Wt* bf16 [N][128].
__global__ __launch_bounds__(256) void pair_gemm_kernel(
        const uint16_t* __restrict__ Xb, const uint16_t* __restrict__ WtL,
        const uint16_t* __restrict__ WtR, const float* __restrict__ bias,
        uint16_t* __restrict__ YL, uint16_t* __restrict__ ZB, int M, int N) {
    const int l   = threadIdx.x & 63;
    const int wv  = threadIdx.x >> 6;
    const int row0 = blockIdx.x * 64 + wv * 16;
    const int ml  = l & 15;
    const int kg  = l >> 4;

    int arow = row0 + ml; if (arow >= M) arow = M - 1;
    const uint16_t* xr = Xb + (size_t)arow * 128 + kg * 8;
    s8v a0 = *(const s8v*)(xr);
    s8v a1 = *(const s8v*)(xr + 32);
    s8v a2 = *(const s8v*)(xr + 64);
    s8v a3 = *(const s8v*)(xr + 96);

    const int drow = row0 + kg * 4;

    for (int n0 = 0; n0 < N; n0 += 16) {
        const uint16_t* wl = WtL + (size_t)(n0 + ml) * 128 + kg * 8;
        const uint16_t* wr = WtR + (size_t)(n0 + ml) * 128 + kg * 8;
        f4v accL = {0.f, 0.f, 0.f, 0.f};
        f4v accR = {0.f, 0.f, 0.f, 0.f};
        accL = __builtin_amdgcn_mfma_f32_16x16x32_bf16(a0, *(const s8v*)(wl), accL, 0, 0, 0);
        accR = __builtin_amdgcn_mfma_f32_16x16x32_bf16(a0, *(const s8v*)(wr), accR, 0, 0, 0);
        accL = __builtin_amdgcn_mfma_f32_16x16x32_bf16(a1, *(const s8v*)(wl + 32), accL, 0, 0, 0);
        accR = __builtin_amdgcn_mfma_f32_16x16x32_bf16(a1, *(const s8v*)(wr + 32), accR, 0, 0, 0);
        accL = __builtin_amdgcn_mfma_f32_16x16x32_bf16(a2, *(const s8v*)(wl + 64), accL, 0, 0, 0);
        accR = __builtin_amdgcn_mfma_f32_16x16x32_bf16(a2, *(const s8v*)(wr + 64), accR, 0, 0, 0);
        accL = __builtin_amdgcn_mfma_f32_16x16x32_bf16(a3, *(const s8v*)(wl + 96), accL, 0, 0, 0);
        accR = __builtin_amdgcn_mfma_f32_16x16x32_bf16(a3, *(const s8v*)(wr + 96), accR, 0, 0, 0);

        float bv = bias[n0 + ml];
#pragma unroll
        for (int r = 0; r < 4; ++r) {
            int g = drow + r;
            if (g < M) {
                YL[(size_t)g * N + n0 + ml] = f2bf(accL[r]);
                ZB[(size_t)g * N + n0 + ml] = f2bf(accR[r] + bv);
            }
        }
    }
}

// ---------------- aggregation epilogues ----------------
// 2 nodes per wave; 32 lanes/node; lane owns 4 channels (uint2 = 4 bf16 = 8B load).
// mean + Z + relu + dropout -> H bf16.
__global__ __launch_bounds__(256) void agg128_kernel(
        const uint16_t* __restrict__ Yl, const uint16_t* __restrict__ Zb,
        const int* __restrict__ rowptr, const int* __restrict__ col,
        uint16_t* __restrict__ H, int n, uint32_t k0, uint32_t k1) {
    int wv = threadIdx.x >> 6, lane = threadIdx.x & 63;
    int half = lane >> 5, sl = lane & 31;
    int node = blockIdx.x * 8 + wv * 2 + half;
    if (node >= n) return;
    const uint2* ylp = (const uint2*)Yl;
    int beg = rowptr[node], end = rowptr[node + 1];
    float a0 = 0.f, a1 = 0.f, a2 = 0.f, a3 = 0.f;
    int e = beg;
    for (; e + 3 < end; e += 4) {
        int j0 = col[e], j1 = col[e + 1], j2 = col[e + 2], j3 = col[e + 3];
        uint2 v0 = ylp[(size_t)j0 * 32 + sl];
        uint2 v1 = ylp[(size_t)j1 * 32 + sl];
        uint2 v2 = ylp[(size_t)j2 * 32 + sl];
        uint2 v3 = ylp[(size_t)j3 * 32 + sl];
        a0 += bflo(v0.x) + bflo(v1.x) + bflo(v2.x) + bflo(v3.x);
        a1 += bfhi(v0.x) + bfhi(v1.x) + bfhi(v2.x) + bfhi(v3.x);
        a2 += bflo(v0.y) + bflo(v1.y) + bflo(v2.y) + bflo(v3.y);
        a3 += bfhi(v0.y) + bfhi(v1.y) + bfhi(v2.y) + bfhi(v3.y);
    }
    for (; e < end; ++e) {
        uint2 v = ylp[(size_t)col[e] * 32 + sl];
        a0 += bflo(v.x); a1 += bfhi(v.x);
        a2 += bflo(v.y); a3 += bfhi(v.y);
    }
    int cnt = end - beg;
    float inv = 1.0f / (float)(cnt > 1 ? cnt : 1);
    uint2 z = ((const uint2*)Zb)[(size_t)node * 32 + sl];
    float h0 = fmaxf(a0 * inv + bflo(z.x), 0.0f);
    float h1 = fmaxf(a1 * inv + bfhi(z.x), 0.0f);
    float h2 = fmaxf(a2 * inv + bflo(z.y), 0.0f);
    float h3 = fmaxf(a3 * inv + bfhi(z.y), 0.0f);
    uint32_t idx = (uint32_t)node * 128u + (uint32_t)sl * 4u;
    h0 = tf_keep(idx,      k0, k1) ? h0 * 2.0f : 0.0f;
    h1 = tf_keep(idx + 1u, k0, k1) ? h1 * 2.0f : 0.0f;
    h2 = tf_keep(idx + 2u, k0, k1) ? h2 * 2.0f : 0.0f;
    h3 = tf_keep(idx + 3u, k0, k1) ? h3 * 2.0f : 0.0f;
    uint2 o;
    o.x = (uint32_t)f2bf(h0) | ((uint32_t)f2bf(h1) << 16);
    o.y = (uint32_t)f2bf(h2) | ((uint32_t)f2bf(h3) << 16);
    ((uint2*)H)[(size_t)node * 32 + sl] = o;
}

// final layer: 2 nodes/wave, 32 lanes/node, lane owns 2 channels (uint = 2 bf16).
// mean + Z -> fp32 out.
__global__ __launch_bounds__(256) void agg64_kernel(
        const uint16_t* __restrict__ Yl, const uint16_t* __restrict__ Zb,
        const int* __restrict__ rowptr, const int* __restrict__ col,
        float* __restrict__ out, int n) {
    int wv = threadIdx.x >> 6, lane = threadIdx.x & 63;
    int half = lane >> 5, sl = lane & 31;
    int node = blockIdx.x * 8 + wv * 2 + half;
    if (node >= n) return;
    const uint32_t* ylp = (const uint32_t*)Yl;
    int beg = rowptr[node], end = rowptr[node + 1];
    float a0 = 0.f, a1 = 0.f;
    int e = beg;
    for (; e + 3 < end; e += 4) {
        int j0 = col[e], j1 = col[e + 1], j2 = col[e + 2], j3 = col[e + 3];
        uint32_t v0 = ylp[(size_t)j0 * 32 + sl];
        uint32_t v1 = ylp[(size_t)j1 * 32 + sl];
        uint32_t v2 = ylp[(size_t)j2 * 32 + sl];
        uint32_t v3 = ylp[(size_t)j3 * 32 + sl];
        a0 += bflo(v0) + bflo(v1) + bflo(v2) + bflo(v3);
        a1 += bfhi(v0) + bfhi(v1) + bfhi(v2) + bfhi(v3);
    }
    for (; e < end; ++e) {
        uint32_t v = ylp[(size_t)col[e] * 32 + sl];
        a0 += bflo(v); a1 += bfhi(v);
    }
    int cnt = end - beg;
    float inv = 1.0f / (float)(cnt > 1 ? cnt : 1);
    uint32_t z = ((const uint32_t*)Zb)[(size_t)node * 32 + sl];
    float2 o;
    o.x = a0 * inv + bflo(z);
    o.y = a1 * inv + bfhi(z);
    *(float2*)(out + (size_t)node * 64 + sl * 2) = o;
}

// ---------------- host ----------------
extern "C" void kernel_launch(void* const* d_in, const int* in_sizes, int n_in,
                              void* d_out, int out_size, void* d_ws, size_t ws_size,
                              hipStream_t stream) {
    const float* x   = (const float*)d_in[0];
    const int*   ei  = (const int*)d_in[1];
    const float* Wl0 = (const float*)d_in[2];
    const float* Wr0 = (const float*)d_in[3];
    const float* b0  = (const float*)d_in[4];
    const float* Wl1 = (const float*)d_in[5];
    const float* Wr1 = (const float*)d_in[6];
    const float* b1  = (const float*)d_in[7];
    const float* Wl2 = (const float*)d_in[8];
    const float* Wr2 = (const float*)d_in[9];
    const float* b2  = (const float*)d_in[10];

    const int N = in_sizes[0] / 128;     // 100000
    const int E = in_sizes[1] / 2;       // 1600000
    const int* srcp = ei;

    const int nA   = (E + ECHUNK - 1) / ECHUNK;
    const int NBUK = (N + 511) >> 9;
    const int L    = NBUK * nA;

    char* ws = (char*)d_ws;
    size_t off = 0;
    auto alloc = [&](size_t bytes) {
        size_t o = off;
        off = (off + bytes + 255) & ~(size_t)255;
        return o;
    };
    int*      rowptr = (int*)(ws + alloc((size_t)(N + 1) * 4));
    int*      deg    = (int*)(ws + alloc((size_t)N * 4));
    int*      bsum   = (int*)(ws + alloc(1024 * 4));
    int*      flag64 = (int*)(ws + alloc(256));
    int*      hist   = (int*)(ws + alloc((size_t)L * 4));
    int*      bofs   = (int*)(ws + alloc((size_t)(L + 1) * 4));
    uint2*    tmp    = (uint2*)(ws + alloc((size_t)E * 8));
    int*      col    = (int*)(ws + alloc((size_t)E * 4));
    uint16_t* Xb     = (uint16_t*)(ws + alloc((size_t)N * 128 * 2));
    uint16_t* Hb     = (uint16_t*)(ws + alloc((size_t)N * 128 * 2));
    uint16_t* Byl    = (uint16_t*)(ws + alloc((size_t)N * 128 * 2));
    uint16_t* Czb    = (uint16_t*)(ws + alloc((size_t)N * 128 * 2));
    uint16_t* Wt0l   = (uint16_t*)(ws + alloc(128 * 128 * 2));
    uint16_t* Wt0r   = (uint16_t*)(ws + alloc(128 * 128 * 2));
    uint16_t* Wt1l   = (uint16_t*)(ws + alloc(128 * 128 * 2));
    uint16_t* Wt1r   = (uint16_t*)(ws + alloc(128 * 128 * 2));
    uint16_t* Wt2l   = (uint16_t*)(ws + alloc(128 * 128 * 2));
    uint16_t* Wt2r   = (uint16_t*)(ws + alloc(128 * 128 * 2));

    // dropout keys: jax.random.split(jax.random.key(42), 2), partitionable scheme.
    uint32_t k00, k01, k10, k11;
    tf2x32(0u, 42u, 0u, 0u, k00, k01);   // dk[0]
    tf2x32(0u, 42u, 0u, 1u, k10, k11);   // dk[1]

    // ---- bucketed CSR build ----
    detect_kernel<<<1, 256, 0, stream>>>(srcp, flag64);
    bucketcount_kernel<<<nA, 256, 0, stream>>>(srcp, flag64, hist, E, nA, NBUK);
    int NBL = (L + 511) / 512;
    scan1_kernel<<<NBL, 512, 0, stream>>>(hist, bofs, bsum, L);
    scan2_kernel<<<1, 64, 0, stream>>>(bsum, NBL);
    scan3_kernel<<<NBL, 512, 0, stream>>>(bofs, bsum, L);
    bucketscatter_kernel<<<nA, 256, 0, stream>>>(srcp, flag64, bofs, tmp, E, nA, NBUK);
    bucketdeg_kernel<<<NBUK, 256, 0, stream>>>(tmp, bofs, deg, nA, N);
    int NBN = (N + 511) / 512;
    scan1_kernel<<<NBN, 512, 0, stream>>>(deg, rowptr, bsum, N);
    scan2_kernel<<<1, 64, 0, stream>>>(bsum, NBN);
    scan3_kernel<<<NBN, 512, 0, stream>>>(rowptr, bsum, N);
    finescatter_kernel<<<NBUK, 256, 0, stream>>>(tmp, bofs, rowptr, col, nA, N);

    // ---- converts ----
    convx_kernel<<<(N * 128 / 4 + 255) / 256, 256, 0, stream>>>(x, Xb, N * 128 / 4);
    WPack wp;
    wp.src[0] = Wl0; wp.dst[0] = Wt0l; wp.n[0] = 128;
    wp.src[1] = Wr0; wp.dst[1] = Wt0r; wp.n[1] = 128;
    wp.src[2] = Wl1; wp.dst[2] = Wt1l; wp.n[2] = 128;
    wp.src[3] = Wr1; wp.dst[3] = Wt1r; wp.n[3] = 128;
    wp.src[4] = Wl2; wp.dst[4] = Wt2l; wp.n[4] = 64;
    wp.src[5] = Wr2; wp.dst[5] = Wt2r; wp.n[5] = 64;
    convw_all_kernel<<<dim3(64, 6), 256, 0, stream>>>(wp);

    dim3 blk(256);
    dim3 gg((N + 63) / 64);
    dim3 gagg((N + 7) / 8);

    // ---- layer 0 ----
    pair_gemm_kernel<<<gg, blk, 0, stream>>>(Xb, Wt0l, Wt0r, b0, Byl, Czb, N, 128);
    agg128_kernel<<<gagg, blk, 0, stream>>>(Byl, Czb, rowptr, col, Hb, N, k00, k01);
    // ---- layer 1 ----
    pair_gemm_kernel<<<gg, blk, 0, stream>>>(Hb, Wt1l, Wt1r, b1, Byl, Czb, N, 128);
    agg128_kernel<<<gagg, blk, 0, stream>>>(Byl, Czb, rowptr, col, Hb, N, k10, k11);
    // ---- layer 2: project (128->64) then aggregate ----
    pair_gemm_kernel<<<gg, blk, 0, stream>>>(Hb, Wt2l, Wt2r, b2, Byl, Czb, N, 64);
    agg64_kernel<<<gagg, blk, 0, stream>>>(Byl, Czb, rowptr, col, (float*)d_out, N);
}